// Round 1
// baseline (1005.349 us; speedup 1.0000x reference)
//
#include <hip/hip_runtime.h>
#include <math.h>

#define B_ 8
#define S_ 1024
#define D_ 1024
constexpr int BS = B_ * S_;

// ---------------- block reduce helper ----------------
__device__ __forceinline__ float block_reduce_sum(float val, float* sh) {
    int tid = threadIdx.x;
    int lane = tid & 63, w = tid >> 6;
    #pragma unroll
    for (int off = 32; off > 0; off >>= 1) val += __shfl_down(val, off, 64);
    if (lane == 0) sh[w] = val;
    __syncthreads();
    int nw = blockDim.x >> 6;
    float total = 0.f;
    for (int i = 0; i < nw; i++) total += sh[i];
    __syncthreads();   // protect sh for next call
    return total;
}

// ---------------- K1: LayerNorm (ddof=1, eps added to std) ----------------
__global__ void ln_kernel(const float* __restrict__ ctx,
                          const float* __restrict__ ln_a,
                          const float* __restrict__ ln_b,
                          float* __restrict__ xln) {
    __shared__ float sh[4];
    int r = blockIdx.x;           // row 0..BS-1
    int tid = threadIdx.x;        // 256
    const float* row = ctx + (size_t)r * D_;
    float v[4];
    float s = 0.f;
    #pragma unroll
    for (int i = 0; i < 4; i++) { v[i] = row[tid + i * 256]; s += v[i]; }
    float total = block_reduce_sum(s, sh);
    float mean = total * (1.0f / D_);
    float sq = 0.f;
    #pragma unroll
    for (int i = 0; i < 4; i++) { float d = v[i] - mean; sq += d * d; }
    float varsum = block_reduce_sum(sq, sh);
    float var = varsum * (1.0f / (D_ - 1));
    float inv = 1.0f / (sqrtf(var) + 1e-6f);
    float* orow = xln + (size_t)r * D_;
    #pragma unroll
    for (int i = 0; i < 4; i++) {
        int d = tid + i * 256;
        orow[d] = ln_a[d] * (v[i] - mean) * inv + ln_b[d];
    }
}

// ---------------- K2/K3: f32 tiled GEMM ----------------
// C[M,N] = A*B.  TRANS_A=false: A is [M,K] row-major.  TRANS_A=true: A is [K,M]
// row-major and we compute A^T*B.  All of M,N multiples of 64; K multiple of 16.
template <bool TRANS_A>
__global__ void gemm64(const float* __restrict__ A, const float* __restrict__ B,
                       float* __restrict__ C, int M, int N, int K) {
    __shared__ float As[16][65];   // [kk][mm]
    __shared__ float Bs[16][65];   // [kk][nn]
    int bn = blockIdx.x * 64, bm = blockIdx.y * 64;
    int tid = threadIdx.x;         // 256
    int tx = tid & 15, ty = tid >> 4;
    float acc[4][4] = {};
    for (int k0 = 0; k0 < K; k0 += 16) {
        if (TRANS_A) {
            #pragma unroll
            for (int i = 0; i < 4; i++) {
                int idx = tid + i * 256;
                int kk = idx >> 6, mm = idx & 63;
                As[kk][mm] = A[(size_t)(k0 + kk) * M + bm + mm];
            }
        } else {
            #pragma unroll
            for (int i = 0; i < 4; i++) {
                int idx = tid + i * 256;
                int mm = idx >> 4, kk = idx & 15;
                As[kk][mm] = A[(size_t)(bm + mm) * K + k0 + kk];
            }
        }
        #pragma unroll
        for (int i = 0; i < 4; i++) {
            int idx = tid + i * 256;
            int kk = idx >> 6, nn = idx & 63;
            Bs[kk][nn] = B[(size_t)(k0 + kk) * N + bn + nn];
        }
        __syncthreads();
        #pragma unroll
        for (int kk = 0; kk < 16; kk++) {
            float a[4], b[4];
            #pragma unroll
            for (int i = 0; i < 4; i++) a[i] = As[kk][ty * 4 + i];
            #pragma unroll
            for (int j = 0; j < 4; j++) b[j] = Bs[kk][tx * 4 + j];
            #pragma unroll
            for (int i = 0; i < 4; i++)
                #pragma unroll
                for (int j = 0; j < 4; j++) acc[i][j] += a[i] * b[j];
        }
        __syncthreads();
    }
    #pragma unroll
    for (int i = 0; i < 4; i++)
        #pragma unroll
        for (int j = 0; j < 4; j++)
            C[(size_t)(bm + ty * 4 + i) * N + bn + tx * 4 + j] = acc[i][j];
}

// ---------------- bias terms: u = Wk^T bq, v = Wq^T bk, c0 = bq.bk ----------
__global__ void bias_terms(const float* __restrict__ Wq, const float* __restrict__ Wk,
                           const float* __restrict__ bq, const float* __restrict__ bk,
                           float* __restrict__ u, float* __restrict__ v,
                           float* __restrict__ c0) {
    __shared__ float sh[4];
    int col = blockIdx.x;
    int tid = threadIdx.x;
    float s = 0.f;
    if (col < D_) {
        for (int d = tid; d < D_; d += 256) s += Wk[(size_t)d * D_ + col] * bq[d];
        s = block_reduce_sum(s, sh);
        if (tid == 0) u[col] = s;
    } else if (col < 2 * D_) {
        int c = col - D_;
        for (int d = tid; d < D_; d += 256) s += Wq[(size_t)d * D_ + c] * bk[d];
        s = block_reduce_sum(s, sh);
        if (tid == 0) v[c] = s;
    } else {
        for (int d = tid; d < D_; d += 256) s += bq[d] * bk[d];
        s = block_reduce_sum(s, sh);
        if (tid == 0) *c0 = s;
    }
}

// ---------------- banded dots: Y_s . x_{s+/-1},  u.x_s, v.x_s ---------------
__global__ void band_dots(const float* __restrict__ Y, const float* __restrict__ X,
                          const float* __restrict__ u, const float* __restrict__ v,
                          float* __restrict__ ydu, float* __restrict__ ydd,
                          float* __restrict__ au, float* __restrict__ av) {
    __shared__ float sh[4];
    int r = blockIdx.x;            // 0..BS-1
    int s = r & (S_ - 1);
    int tid = threadIdx.x;         // 256
    const float* yrow = Y + (size_t)r * D_;
    const float* xrow = X + (size_t)r * D_;
    const float* xup = X + (size_t)(r + 1) * D_;
    const float* xdn = X + (size_t)(r - 1) * D_;
    bool has_up = (s < S_ - 1), has_dn = (s > 0);
    float s_up = 0, s_dn = 0, s_u = 0, s_v = 0;
    for (int d = tid; d < D_; d += 256) {
        float yv = yrow[d];
        if (has_up) s_up += yv * xup[d];
        if (has_dn) s_dn += yv * xdn[d];
        float xv = xrow[d];
        s_u += u[d] * xv;
        s_v += v[d] * xv;
    }
    s_up = block_reduce_sum(s_up, sh);
    s_dn = block_reduce_sum(s_dn, sh);
    s_u  = block_reduce_sum(s_u, sh);
    s_v  = block_reduce_sum(s_v, sh);
    if (tid == 0) { ydu[r] = s_up; ydd[r] = s_dn; au[r] = s_u; av[r] = s_v; }
}

// ---------------- banded softmax -> Pup/Pdn/bg per row ----------------------
__global__ void softmax_band(const float* __restrict__ ydu, const float* __restrict__ ydd,
                             const float* __restrict__ au, const float* __restrict__ av,
                             const float* __restrict__ c0p, const int* __restrict__ eos,
                             float* __restrict__ Pup, float* __restrict__ Pdn,
                             float* __restrict__ bg) {
    int r = blockIdx.x * blockDim.x + threadIdx.x;
    if (r >= BS) return;
    int b = r >> 10, s = r & (S_ - 1);
    float c0 = *c0p;
    const float inv_d = 1.0f / D_;
    bool mu = false, md = false;
    float su = 0.f, sd = 0.f;
    if (s < S_ - 1) {
        mu = eos[(size_t)b * S_ * S_ + (size_t)s * S_ + (s + 1)] != 0;
        su = (ydu[r] + av[r] + au[r + 1] + c0) * inv_d;
    }
    if (s > 0) {
        md = eos[(size_t)b * S_ * S_ + (size_t)s * S_ + (s - 1)] != 0;
        sd = (ydd[r] + av[r] + au[r - 1] + c0) * inv_d;
    }
    float pu, pd, pb;
    if (mu && md) {
        float m = fmaxf(su, sd);
        float eu = expf(su - m), ed = expf(sd - m);
        float inv = 1.0f / (eu + ed);
        pu = eu * inv; pd = ed * inv; pb = 0.f;
    } else if (mu) { pu = 1.f; pd = 0.f; pb = 0.f; }
    else if (md)   { pu = 0.f; pd = 1.f; pb = 0.f; }
    else           { pu = pd = pb = 1.0f / S_; }
    Pup[r] = pu; Pdn[r] = pd; bg[r] = pb;
}

// ---------------- prefix sums of band logs (f64) ----------------------------
__global__ void prefix_kernel(const float* __restrict__ Pup, const float* __restrict__ Pdn,
                              double* __restrict__ C) {
    int b = blockIdx.x;
    if (threadIdx.x != 0) return;
    size_t base = (size_t)b * S_;
    double acc = 0.0;
    C[base] = 0.0;
    for (int t = 0; t < S_ - 1; t++) {
        float p = sqrtf(Pup[base + t] * Pdn[base + t + 1] + 1e-9f) + 1e-9f;
        acc += log((double)p);
        C[base + t + 1] = acc;
    }
}

// ---------------- final outputs: g and neibor -------------------------------
__global__ void write_out(const float* __restrict__ Pup, const float* __restrict__ Pdn,
                          const float* __restrict__ bg, const double* __restrict__ C,
                          float* __restrict__ out) {
    int r = blockIdx.x;            // (b, s) row, 0..BS-1
    int b = r >> 10, s = r & (S_ - 1);
    size_t rowbase = (size_t)r * S_;
    size_t bb = (size_t)b * S_;
    float pu_s = (s < S_ - 1) ? Pup[r] : 0.f;
    float pd_s = (s > 0) ? Pdn[r] : 0.f;
    float bg_s = bg[r];
    double C_s = C[r];
    int t0 = threadIdx.x * 4;
    float* gp = out;                               // g  [B,S,S]
    float* np = out + (size_t)B_ * S_ * S_;        // neibor [B,S,S]
    float4 gv, nv;
    #pragma unroll
    for (int j = 0; j < 4; j++) {
        int t = t0 + j;
        float P_st = (t == s + 1) ? pu_s : ((t == s - 1) ? pd_s : bg_s);
        float P_ts;
        if (t == s - 1)      P_ts = Pup[bb + t];   // P[t, t+1]
        else if (t == s + 1) P_ts = Pdn[bb + t];   // P[t, t-1]
        else                 P_ts = bg[bb + t];
        float neib = sqrtf(P_st * P_ts + 1e-9f);
        float g;
        if (t == s) {
            g = neib;                               // diagonal: neibor value
        } else {
            double diff = (t > s) ? (C[bb + t] - C_s) : (C_s - C[bb + t]);
            g = expf((float)diff) + 1e-9f;
        }
        ((float*)&gv)[j] = g;
        ((float*)&nv)[j] = neib;
    }
    *(float4*)(gp + rowbase + t0) = gv;
    *(float4*)(np + rowbase + t0) = nv;
}

// ---------------- launcher ---------------------------------------------------
extern "C" void kernel_launch(void* const* d_in, const int* in_sizes, int n_in,
                              void* d_out, int out_size, void* d_ws, size_t ws_size,
                              hipStream_t stream) {
    const float* ctx  = (const float*)d_in[0];
    const int*   eos  = (const int*)d_in[1];
    const float* Wq   = (const float*)d_in[2];
    const float* bq   = (const float*)d_in[3];
    const float* Wk   = (const float*)d_in[4];
    const float* bk   = (const float*)d_in[5];
    const float* ln_a = (const float*)d_in[6];
    const float* ln_b = (const float*)d_in[7];
    float* out = (float*)d_out;

    char* ws = (char*)d_ws;
    size_t off = 0;
    auto alloc = [&](size_t bytes) {
        void* p = ws + off;
        off += (bytes + 255) & ~(size_t)255;
        return p;
    };
    float*  Xln = (float*)alloc((size_t)BS * D_ * 4);
    float*  Mm  = (float*)alloc((size_t)D_ * D_ * 4);
    float*  Y   = (float*)alloc((size_t)BS * D_ * 4);
    float*  u   = (float*)alloc(D_ * 4);
    float*  v   = (float*)alloc(D_ * 4);
    float*  c0  = (float*)alloc(4);
    float*  ydu = (float*)alloc(BS * 4);
    float*  ydd = (float*)alloc(BS * 4);
    float*  au  = (float*)alloc(BS * 4);
    float*  av  = (float*)alloc(BS * 4);
    float*  Pup = (float*)alloc(BS * 4);
    float*  Pdn = (float*)alloc(BS * 4);
    float*  bg  = (float*)alloc(BS * 4);
    double* Cp  = (double*)alloc(BS * 8);

    // 1. LayerNorm
    ln_kernel<<<BS, 256, 0, stream>>>(ctx, ln_a, ln_b, Xln);
    // 2. M = Wq^T Wk
    gemm64<true><<<dim3(D_ / 64, D_ / 64), 256, 0, stream>>>(Wq, Wk, Mm, D_, D_, D_);
    // 3. bias terms
    bias_terms<<<2 * D_ + 1, 256, 0, stream>>>(Wq, Wk, bq, bk, u, v, c0);
    // 4. Y = Xln @ M
    gemm64<false><<<dim3(D_ / 64, BS / 64), 256, 0, stream>>>(Xln, Mm, Y, BS, D_, D_);
    // 5. banded dots
    band_dots<<<BS, 256, 0, stream>>>(Y, Xln, u, v, ydu, ydd, au, av);
    // 6. banded softmax
    softmax_band<<<BS / 256, 256, 0, stream>>>(ydu, ydd, au, av, c0, eos, Pup, Pdn, bg);
    // 7. prefix log-sums
    prefix_kernel<<<B_, 64, 0, stream>>>(Pup, Pdn, Cp);
    // 8. outputs
    write_out<<<BS, 256, 0, stream>>>(Pup, Pdn, bg, Cp, out);
}

// Round 2
// 231.416 us; speedup vs baseline: 4.3443x; 4.3443x over previous
//
#include <hip/hip_runtime.h>
#include <math.h>

#define B_ 8
#define S_ 1024
#define D_ 1024
constexpr int BS = B_ * S_;

typedef short bf16x8 __attribute__((ext_vector_type(8)));
typedef float f32x4 __attribute__((ext_vector_type(4)));

__device__ __forceinline__ unsigned short f2bf(float f) {
    unsigned int u = __float_as_uint(f);
    u += 0x7fffu + ((u >> 16) & 1u);
    return (unsigned short)(u >> 16);
}
__device__ __forceinline__ float bf2f(unsigned short h) {
    return __uint_as_float(((unsigned int)h) << 16);
}

// ---------------- block reduce helper ----------------
__device__ __forceinline__ float block_reduce_sum(float val, float* sh) {
    int tid = threadIdx.x;
    int lane = tid & 63, w = tid >> 6;
    #pragma unroll
    for (int off = 32; off > 0; off >>= 1) val += __shfl_down(val, off, 64);
    if (lane == 0) sh[w] = val;
    __syncthreads();
    int nw = blockDim.x >> 6;
    float total = 0.f;
    for (int i = 0; i < nw; i++) total += sh[i];
    __syncthreads();
    return total;
}

// ---------------- K1: LayerNorm (ddof=1, eps on std) -> bf16 ----------------
__global__ void ln_kernel(const float* __restrict__ ctx,
                          const float* __restrict__ ln_a,
                          const float* __restrict__ ln_b,
                          unsigned short* __restrict__ xb) {
    __shared__ float sh[4];
    int r = blockIdx.x;
    int tid = threadIdx.x;        // 256
    const float* row = ctx + (size_t)r * D_;
    float v[4];
    float s = 0.f;
    #pragma unroll
    for (int i = 0; i < 4; i++) { v[i] = row[tid + i * 256]; s += v[i]; }
    float total = block_reduce_sum(s, sh);
    float mean = total * (1.0f / D_);
    float sq = 0.f;
    #pragma unroll
    for (int i = 0; i < 4; i++) { float d = v[i] - mean; sq += d * d; }
    float varsum = block_reduce_sum(sq, sh);
    float var = varsum * (1.0f / (D_ - 1));
    float inv = 1.0f / (sqrtf(var) + 1e-6f);
    unsigned short* orow = xb + (size_t)r * D_;
    #pragma unroll
    for (int i = 0; i < 4; i++) {
        int d = tid + i * 256;
        orow[d] = f2bf(ln_a[d] * (v[i] - mean) * inv + ln_b[d]);
    }
}

// ---------------- transpose + convert f32 -> bf16 ---------------------------
// out[j][i] = in[i][j], n x n, n multiple of 32
__global__ void transpose_bf16(const float* __restrict__ in,
                               unsigned short* __restrict__ out, int n) {
    __shared__ float t[32][33];
    int bx = blockIdx.x * 32, by = blockIdx.y * 32;
    int tx = threadIdx.x, ty = threadIdx.y;   // 32 x 8
    #pragma unroll
    for (int i = 0; i < 32; i += 8)
        t[ty + i][tx] = in[(size_t)(by + ty + i) * n + bx + tx];
    __syncthreads();
    #pragma unroll
    for (int i = 0; i < 32; i += 8)
        out[(size_t)(bx + ty + i) * n + by + tx] = f2bf(t[tx][ty + i]);
}

// ---------------- MFMA bf16 GEMM: C = A * B^T ------------------------------
// A [M][K] bf16 row-major, Bt [N][K] bf16 row-major, C [M][N] bf16.
// Tile 128x128, BK=64, 256 threads (4 waves, 2x2 of 64x64 per wave).
// LDS chunk XOR-swizzle: chunk (16B) c of row r stored at c ^ (r&7).
__global__ __launch_bounds__(256) void gemm_bt(
    const unsigned short* __restrict__ A,
    const unsigned short* __restrict__ Bt,
    unsigned short* __restrict__ C,
    int M, int N, int K) {
    __shared__ __align__(16) unsigned short As[128 * 64];
    __shared__ __align__(16) unsigned short Bs[128 * 64];
    const int tid = threadIdx.x;
    const int wave = tid >> 6, lane = tid & 63;
    const int bm = blockIdx.y * 128, bn = blockIdx.x * 128;
    const int lrow8 = lane >> 3;     // 0..7
    const int pchunk = lane & 7;     // physical 16B chunk within row
    const int m_lane = lane & 15, quad = lane >> 4;
    const int wr = wave >> 1, wc = wave & 1;

    f32x4 acc[4][4] = {};

    for (int k0 = 0; k0 < K; k0 += 64) {
        #pragma unroll
        for (int c = 0; c < 4; c++) {
            int row = wave * 32 + c * 8 + lrow8;
            int gchunk = pchunk ^ (row & 7);
            const unsigned short* gpA = A + (size_t)(bm + row) * K + k0 + gchunk * 8;
            const unsigned short* gpB = Bt + (size_t)(bn + row) * K + k0 + gchunk * 8;
            __builtin_amdgcn_global_load_lds(
                (const __attribute__((address_space(1))) void*)gpA,
                (__attribute__((address_space(3))) void*)(As + (wave * 32 + c * 8) * 64),
                16, 0, 0);
            __builtin_amdgcn_global_load_lds(
                (const __attribute__((address_space(1))) void*)gpB,
                (__attribute__((address_space(3))) void*)(Bs + (wave * 32 + c * 8) * 64),
                16, 0, 0);
        }
        __syncthreads();
        #pragma unroll
        for (int kk = 0; kk < 2; kk++) {
            bf16x8 af[4], bfr[4];
            #pragma unroll
            for (int i = 0; i < 4; i++) {
                int row = wr * 64 + i * 16 + m_lane;
                int lchunk = kk * 4 + quad;
                af[i] = *(const bf16x8*)(As + row * 64 + (lchunk ^ (row & 7)) * 8);
            }
            #pragma unroll
            for (int j = 0; j < 4; j++) {
                int row = wc * 64 + j * 16 + m_lane;
                int lchunk = kk * 4 + quad;
                bfr[j] = *(const bf16x8*)(Bs + row * 64 + (lchunk ^ (row & 7)) * 8);
            }
            #pragma unroll
            for (int i = 0; i < 4; i++)
                #pragma unroll
                for (int j = 0; j < 4; j++)
                    acc[i][j] = __builtin_amdgcn_mfma_f32_16x16x32_bf16(
                        af[i], bfr[j], acc[i][j], 0, 0, 0);
        }
        __syncthreads();
    }
    #pragma unroll
    for (int i = 0; i < 4; i++)
        #pragma unroll
        for (int j = 0; j < 4; j++)
            #pragma unroll
            for (int r = 0; r < 4; r++) {
                int row = bm + wr * 64 + i * 16 + quad * 4 + r;
                int col = bn + wc * 64 + j * 16 + m_lane;
                C[(size_t)row * N + col] = f2bf(acc[i][j][r]);
            }
}

// ---------------- bias terms: u = Wk^T bq, v = Wq^T bk, c0 = bq.bk ----------
__global__ void bias_terms(const float* __restrict__ Wq, const float* __restrict__ Wk,
                           const float* __restrict__ bq, const float* __restrict__ bk,
                           float* __restrict__ u, float* __restrict__ v,
                           float* __restrict__ c0) {
    __shared__ float sh[4];
    int col = blockIdx.x;
    int tid = threadIdx.x;
    float s = 0.f;
    if (col < D_) {
        for (int d = tid; d < D_; d += 256) s += Wk[(size_t)d * D_ + col] * bq[d];
        s = block_reduce_sum(s, sh);
        if (tid == 0) u[col] = s;
    } else if (col < 2 * D_) {
        int c = col - D_;
        for (int d = tid; d < D_; d += 256) s += Wq[(size_t)d * D_ + c] * bk[d];
        s = block_reduce_sum(s, sh);
        if (tid == 0) v[c] = s;
    } else {
        for (int d = tid; d < D_; d += 256) s += bq[d] * bk[d];
        s = block_reduce_sum(s, sh);
        if (tid == 0) *c0 = s;
    }
}

// ---------------- banded dots (bf16 inputs, f32 accumulate) -----------------
__global__ void band_dots(const unsigned short* __restrict__ Y,
                          const unsigned short* __restrict__ X,
                          const float* __restrict__ u, const float* __restrict__ v,
                          float* __restrict__ ydu, float* __restrict__ ydd,
                          float* __restrict__ au, float* __restrict__ av) {
    __shared__ float sh[4];
    int r = blockIdx.x;
    int s = r & (S_ - 1);
    int tid = threadIdx.x;         // 256
    bool has_up = (s < S_ - 1), has_dn = (s > 0);
    const unsigned short* yrow = Y + (size_t)r * D_;
    const unsigned short* xrow = X + (size_t)r * D_;
    const unsigned short* xup = X + (size_t)(r + 1) * D_;
    const unsigned short* xdn = X + (size_t)(r - 1) * D_;
    int d0 = tid * 4;
    ushort4 yv4 = *(const ushort4*)(yrow + d0);
    ushort4 xv4 = *(const ushort4*)(xrow + d0);
    ushort4 xu4 = has_up ? *(const ushort4*)(xup + d0) : make_ushort4(0, 0, 0, 0);
    ushort4 xd4 = has_dn ? *(const ushort4*)(xdn + d0) : make_ushort4(0, 0, 0, 0);
    float4 uv = *(const float4*)(u + d0);
    float4 vv = *(const float4*)(v + d0);
    float s_up = 0, s_dn = 0, s_u = 0, s_v = 0;
    {
        float y0 = bf2f(yv4.x), y1 = bf2f(yv4.y), y2 = bf2f(yv4.z), y3 = bf2f(yv4.w);
        float x0 = bf2f(xv4.x), x1 = bf2f(xv4.y), x2 = bf2f(xv4.z), x3 = bf2f(xv4.w);
        s_up = y0 * bf2f(xu4.x) + y1 * bf2f(xu4.y) + y2 * bf2f(xu4.z) + y3 * bf2f(xu4.w);
        s_dn = y0 * bf2f(xd4.x) + y1 * bf2f(xd4.y) + y2 * bf2f(xd4.z) + y3 * bf2f(xd4.w);
        s_u = uv.x * x0 + uv.y * x1 + uv.z * x2 + uv.w * x3;
        s_v = vv.x * x0 + vv.y * x1 + vv.z * x2 + vv.w * x3;
    }
    s_up = block_reduce_sum(s_up, sh);
    s_dn = block_reduce_sum(s_dn, sh);
    s_u  = block_reduce_sum(s_u, sh);
    s_v  = block_reduce_sum(s_v, sh);
    if (tid == 0) { ydu[r] = s_up; ydd[r] = s_dn; au[r] = s_u; av[r] = s_v; }
}

// ---------------- banded softmax -> Pup/Pdn/bg per row ----------------------
__global__ void softmax_band(const float* __restrict__ ydu, const float* __restrict__ ydd,
                             const float* __restrict__ au, const float* __restrict__ av,
                             const float* __restrict__ c0p, const int* __restrict__ eos,
                             float* __restrict__ Pup, float* __restrict__ Pdn,
                             float* __restrict__ bg) {
    int r = blockIdx.x * blockDim.x + threadIdx.x;
    if (r >= BS) return;
    int b = r >> 10, s = r & (S_ - 1);
    float c0 = *c0p;
    const float inv_d = 1.0f / D_;
    bool mu = false, md = false;
    float su = 0.f, sd = 0.f;
    if (s < S_ - 1) {
        mu = eos[(size_t)b * S_ * S_ + (size_t)s * S_ + (s + 1)] != 0;
        su = (ydu[r] + av[r] + au[r + 1] + c0) * inv_d;
    }
    if (s > 0) {
        md = eos[(size_t)b * S_ * S_ + (size_t)s * S_ + (s - 1)] != 0;
        sd = (ydd[r] + av[r] + au[r - 1] + c0) * inv_d;
    }
    float pu, pd, pb;
    if (mu && md) {
        float m = fmaxf(su, sd);
        float eu = expf(su - m), ed = expf(sd - m);
        float inv = 1.0f / (eu + ed);
        pu = eu * inv; pd = ed * inv; pb = 0.f;
    } else if (mu) { pu = 1.f; pd = 0.f; pb = 0.f; }
    else if (md)   { pu = 0.f; pd = 1.f; pb = 0.f; }
    else           { pu = pd = pb = 1.0f / S_; }
    Pup[r] = pu; Pdn[r] = pd; bg[r] = pb;
}

// ---------------- parallel prefix sums of band logs (f64) -------------------
__global__ void prefix_kernel(const float* __restrict__ Pup, const float* __restrict__ Pdn,
                              double* __restrict__ C) {
    __shared__ double wsum[16];
    int b = blockIdx.x;
    int t = threadIdx.x;           // 0..1023
    size_t base = (size_t)b * S_;
    double l = 0.0;
    if (t < S_ - 1) {
        float p = sqrtf(Pup[base + t] * Pdn[base + t + 1] + 1e-9f) + 1e-9f;
        l = log((double)p);
    }
    int lane = t & 63, w = t >> 6;
    double v = l;
    #pragma unroll
    for (int off = 1; off < 64; off <<= 1) {
        double o = __shfl_up(v, off, 64);
        if (lane >= off) v += o;
    }
    if (lane == 63) wsum[w] = v;
    __syncthreads();
    if (t == 0) {
        double acc = 0.0;
        #pragma unroll
        for (int i = 0; i < 16; i++) { double x = wsum[i]; wsum[i] = acc; acc += x; }
    }
    __syncthreads();
    v += wsum[w];
    if (t == 0) C[base] = 0.0;
    if (t < S_ - 1) C[base + t + 1] = v;
}

// ---------------- final outputs: g and neibor -------------------------------
__global__ void write_out(const float* __restrict__ Pup, const float* __restrict__ Pdn,
                          const float* __restrict__ bg, const double* __restrict__ C,
                          float* __restrict__ out) {
    int r = blockIdx.x;            // (b, s) row
    int b = r >> 10, s = r & (S_ - 1);
    size_t rowbase = (size_t)r * S_;
    size_t bb = (size_t)b * S_;
    float pu_s = (s < S_ - 1) ? Pup[r] : 0.f;
    float pd_s = (s > 0) ? Pdn[r] : 0.f;
    float bg_s = bg[r];
    double C_s = C[r];
    int t0 = threadIdx.x * 4;
    float* gp = out;
    float* np = out + (size_t)B_ * S_ * S_;
    float4 gv, nv;
    #pragma unroll
    for (int j = 0; j < 4; j++) {
        int t = t0 + j;
        float P_st = (t == s + 1) ? pu_s : ((t == s - 1) ? pd_s : bg_s);
        float P_ts;
        if (t == s - 1)      P_ts = Pup[bb + t];
        else if (t == s + 1) P_ts = Pdn[bb + t];
        else                 P_ts = bg[bb + t];
        float neib = sqrtf(P_st * P_ts + 1e-9f);
        float g;
        if (t == s) {
            g = neib;
        } else {
            double diff = (t > s) ? (C[bb + t] - C_s) : (C_s - C[bb + t]);
            g = expf((float)diff) + 1e-9f;
        }
        ((float*)&gv)[j] = g;
        ((float*)&nv)[j] = neib;
    }
    *(float4*)(gp + rowbase + t0) = gv;
    *(float4*)(np + rowbase + t0) = nv;
}

// ---------------- launcher ---------------------------------------------------
extern "C" void kernel_launch(void* const* d_in, const int* in_sizes, int n_in,
                              void* d_out, int out_size, void* d_ws, size_t ws_size,
                              hipStream_t stream) {
    const float* ctx  = (const float*)d_in[0];
    const int*   eos  = (const int*)d_in[1];
    const float* Wq   = (const float*)d_in[2];
    const float* bq   = (const float*)d_in[3];
    const float* Wk   = (const float*)d_in[4];
    const float* bk   = (const float*)d_in[5];
    const float* ln_a = (const float*)d_in[6];
    const float* ln_b = (const float*)d_in[7];
    float* out = (float*)d_out;

    char* ws = (char*)d_ws;
    size_t off = 0;
    auto alloc = [&](size_t bytes) {
        void* p = ws + off;
        off += (bytes + 255) & ~(size_t)255;
        return p;
    };
    unsigned short* Xb  = (unsigned short*)alloc((size_t)BS * D_ * 2);
    unsigned short* Wqt = (unsigned short*)alloc((size_t)D_ * D_ * 2);
    unsigned short* Wkt = (unsigned short*)alloc((size_t)D_ * D_ * 2);
    unsigned short* Mt  = (unsigned short*)alloc((size_t)D_ * D_ * 2);
    unsigned short* Yb  = (unsigned short*)alloc((size_t)BS * D_ * 2);
    float*  u   = (float*)alloc(D_ * 4);
    float*  v   = (float*)alloc(D_ * 4);
    float*  c0  = (float*)alloc(4);
    float*  ydu = (float*)alloc(BS * 4);
    float*  ydd = (float*)alloc(BS * 4);
    float*  au  = (float*)alloc(BS * 4);
    float*  av  = (float*)alloc(BS * 4);
    float*  Pup = (float*)alloc(BS * 4);
    float*  Pdn = (float*)alloc(BS * 4);
    float*  bg  = (float*)alloc(BS * 4);
    double* Cp  = (double*)alloc(BS * 8);

    // 1. LayerNorm -> bf16
    ln_kernel<<<BS, 256, 0, stream>>>(ctx, ln_a, ln_b, Xb);
    // 2. transpose-convert Wq, Wk
    transpose_bf16<<<dim3(32, 32), dim3(32, 8), 0, stream>>>(Wq, Wqt, D_);
    transpose_bf16<<<dim3(32, 32), dim3(32, 8), 0, stream>>>(Wk, Wkt, D_);
    // 3. Mt[n][k] = sum_d Wk[d][n] Wq[d][k]  (= (Wq^T Wk) transposed)
    gemm_bt<<<dim3(8, 8), 256, 0, stream>>>(Wkt, Wqt, Mt, D_, D_, D_);
    // 4. bias terms
    bias_terms<<<2 * D_ + 1, 256, 0, stream>>>(Wq, Wk, bq, bk, u, v, c0);
    // 5. Y[s][n] = sum_k Xb[s][k] Mt[n][k]
    gemm_bt<<<dim3(8, 64), 256, 0, stream>>>(Xb, Mt, Yb, BS, D_, D_);
    // 6. banded dots
    band_dots<<<BS, 256, 0, stream>>>(Yb, Xb, u, v, ydu, ydd, au, av);
    // 7. banded softmax
    softmax_band<<<BS / 256, 256, 0, stream>>>(ydu, ydd, au, av, c0, eos, Pup, Pdn, bg);
    // 8. prefix log-sums (parallel scan)
    prefix_kernel<<<B_, 1024, 0, stream>>>(Pup, Pdn, Cp);
    // 9. outputs
    write_out<<<BS, 256, 0, stream>>>(Pup, Pdn, bg, Cp, out);
}

// Round 3
// 217.832 us; speedup vs baseline: 4.6152x; 1.0624x over previous
//
#include <hip/hip_runtime.h>
#include <math.h>

#define B_ 8
#define S_ 1024
#define D_ 1024
constexpr int BS = B_ * S_;

typedef short bf16x8 __attribute__((ext_vector_type(8)));
typedef float f32x4 __attribute__((ext_vector_type(4)));

__device__ __forceinline__ unsigned short f2bf(float f) {
    unsigned int u = __float_as_uint(f);
    u += 0x7fffu + ((u >> 16) & 1u);
    return (unsigned short)(u >> 16);
}
__device__ __forceinline__ float bf2f(unsigned short h) {
    return __uint_as_float(((unsigned int)h) << 16);
}

__device__ __forceinline__ float block_reduce_sum(float val, float* sh) {
    int tid = threadIdx.x;
    int lane = tid & 63, w = tid >> 6;
    #pragma unroll
    for (int off = 32; off > 0; off >>= 1) val += __shfl_down(val, off, 64);
    if (lane == 0) sh[w] = val;
    __syncthreads();
    int nw = blockDim.x >> 6;
    float total = 0.f;
    for (int i = 0; i < nw; i++) total += sh[i];
    __syncthreads();
    return total;
}

// ---------------- LayerNorm (ddof=1, eps on std) -> bf16 ----------------
__global__ void ln_kernel(const float* __restrict__ ctx,
                          const float* __restrict__ ln_a,
                          const float* __restrict__ ln_b,
                          unsigned short* __restrict__ xb) {
    __shared__ float sh[4];
    int r = blockIdx.x;
    int tid = threadIdx.x;        // 256
    const float* row = ctx + (size_t)r * D_;
    float v[4];
    float s = 0.f;
    #pragma unroll
    for (int i = 0; i < 4; i++) { v[i] = row[tid + i * 256]; s += v[i]; }
    float total = block_reduce_sum(s, sh);
    float mean = total * (1.0f / D_);
    float sq = 0.f;
    #pragma unroll
    for (int i = 0; i < 4; i++) { float d = v[i] - mean; sq += d * d; }
    float varsum = block_reduce_sum(sq, sh);
    float var = varsum * (1.0f / (D_ - 1));
    float inv = 1.0f / (sqrtf(var) + 1e-6f);
    unsigned short* orow = xb + (size_t)r * D_;
    #pragma unroll
    for (int i = 0; i < 4; i++) {
        int d = tid + i * 256;
        orow[d] = f2bf(ln_a[d] * (v[i] - mean) * inv + ln_b[d]);
    }
}

// ---------------- transpose + convert f32 -> bf16 (Wq & Wk in one) ----------
__global__ void transpose2_bf16(const float* __restrict__ inq,
                                const float* __restrict__ ink,
                                unsigned short* __restrict__ outq,
                                unsigned short* __restrict__ outk) {
    __shared__ float t[32][33];
    const float* in = blockIdx.z ? ink : inq;
    unsigned short* out = blockIdx.z ? outk : outq;
    int bx = blockIdx.x * 32, by = blockIdx.y * 32;
    int tx = threadIdx.x, ty = threadIdx.y;   // 32 x 8
    #pragma unroll
    for (int i = 0; i < 32; i += 8)
        t[ty + i][tx] = in[(size_t)(by + ty + i) * D_ + bx + tx];
    __syncthreads();
    #pragma unroll
    for (int i = 0; i < 32; i += 8)
        out[(size_t)(bx + ty + i) * D_ + by + tx] = f2bf(t[tx][ty + i]);
}

// ---------------- bias terms (coalesced, atomic accumulate) -----------------
// u += Wk^T bq, v += Wq^T bk, c0 += bq.bk   (targets pre-zeroed)
__global__ void bias_terms(const float* __restrict__ Wq, const float* __restrict__ Wk,
                           const float* __restrict__ bq, const float* __restrict__ bk,
                           float* __restrict__ u, float* __restrict__ v,
                           float* __restrict__ c0) {
    int b = blockIdx.x;            // 8 blocks, 128 rows each
    int tid = threadIdx.x;         // 256
    float ua[4] = {}, va[4] = {};
    int d0 = b * 128;
    for (int d = d0; d < d0 + 128; d++) {
        float bqd = bq[d], bkd = bk[d];
        const float* wkr = Wk + (size_t)d * D_;
        const float* wqr = Wq + (size_t)d * D_;
        #pragma unroll
        for (int i = 0; i < 4; i++) {
            int c = tid + i * 256;
            ua[i] += wkr[c] * bqd;
            va[i] += wqr[c] * bkd;
        }
    }
    #pragma unroll
    for (int i = 0; i < 4; i++) {
        atomicAdd(&u[tid + i * 256], ua[i]);
        atomicAdd(&v[tid + i * 256], va[i]);
    }
    if (tid < 128) atomicAdd(c0, bq[d0 + tid] * bk[d0 + tid]);
}

// ---------------- MFMA bf16 GEMM 64x64 tile: C = A * B^T (for Mt) ----------
__global__ __launch_bounds__(256) void gemm_bt64(
    const unsigned short* __restrict__ A,
    const unsigned short* __restrict__ Bt,
    unsigned short* __restrict__ C,
    int M, int N, int K) {
    __shared__ __align__(16) unsigned short As[64 * 64];
    __shared__ __align__(16) unsigned short Bs[64 * 64];
    const int tid = threadIdx.x;
    const int wave = tid >> 6, lane = tid & 63;
    const int bm = blockIdx.y * 64, bn = blockIdx.x * 64;
    const int lrow8 = lane >> 3;
    const int pchunk = lane & 7;
    const int m_lane = lane & 15, quad = lane >> 4;
    const int wr = wave >> 1, wc = wave & 1;

    f32x4 acc[2][2] = {};

    for (int k0 = 0; k0 < K; k0 += 64) {
        #pragma unroll
        for (int c = 0; c < 2; c++) {
            int row = wave * 16 + c * 8 + lrow8;
            int gchunk = pchunk ^ (row & 7);
            const unsigned short* gpA = A + (size_t)(bm + row) * K + k0 + gchunk * 8;
            const unsigned short* gpB = Bt + (size_t)(bn + row) * K + k0 + gchunk * 8;
            __builtin_amdgcn_global_load_lds(
                (const __attribute__((address_space(1))) void*)gpA,
                (__attribute__((address_space(3))) void*)(As + (wave * 16 + c * 8) * 64),
                16, 0, 0);
            __builtin_amdgcn_global_load_lds(
                (const __attribute__((address_space(1))) void*)gpB,
                (__attribute__((address_space(3))) void*)(Bs + (wave * 16 + c * 8) * 64),
                16, 0, 0);
        }
        __syncthreads();
        #pragma unroll
        for (int kk = 0; kk < 2; kk++) {
            bf16x8 af[2], bfr[2];
            #pragma unroll
            for (int i = 0; i < 2; i++) {
                int row = wr * 32 + i * 16 + m_lane;
                int lchunk = kk * 4 + quad;
                af[i] = *(const bf16x8*)(As + row * 64 + (lchunk ^ (row & 7)) * 8);
            }
            #pragma unroll
            for (int j = 0; j < 2; j++) {
                int row = wc * 32 + j * 16 + m_lane;
                int lchunk = kk * 4 + quad;
                bfr[j] = *(const bf16x8*)(Bs + row * 64 + (lchunk ^ (row & 7)) * 8);
            }
            #pragma unroll
            for (int i = 0; i < 2; i++)
                #pragma unroll
                for (int j = 0; j < 2; j++)
                    acc[i][j] = __builtin_amdgcn_mfma_f32_16x16x32_bf16(
                        af[i], bfr[j], acc[i][j], 0, 0, 0);
        }
        __syncthreads();
    }
    #pragma unroll
    for (int i = 0; i < 2; i++)
        #pragma unroll
        for (int j = 0; j < 2; j++)
            #pragma unroll
            for (int r = 0; r < 4; r++) {
                int row = bm + wr * 32 + i * 16 + quad * 4 + r;
                int col = bn + wc * 32 + j * 16 + m_lane;
                C[(size_t)row * N + col] = f2bf(acc[i][j][r]);
            }
}

// ---------------- MFMA GEMM 128x128 + fused banded dots --------------------
// Y = Xb * Mt^T is computed per-tile in registers and immediately reduced:
//   ydu[r] += sum_c Y[r][c] * x[r+1][c],  ydd[r] += sum_c Y[r][c] * x[r-1][c]
//   au[r]  += sum_c u[c] * x[r][c],       av[r]  += sum_c v[c] * x[r][c]
// (targets pre-zeroed; Y never hits memory)
__global__ __launch_bounds__(256) void gemm_fused(
    const unsigned short* __restrict__ A,   // Xb [BS][D]
    const unsigned short* __restrict__ Bt,  // Mt [D][D]
    const float* __restrict__ u, const float* __restrict__ v,
    float* __restrict__ ydu, float* __restrict__ ydd,
    float* __restrict__ au, float* __restrict__ av,
    int M, int N, int K) {
    __shared__ __align__(16) unsigned short As[128 * 64];
    __shared__ __align__(16) unsigned short Bs[128 * 64];
    const int tid = threadIdx.x;
    const int wave = tid >> 6, lane = tid & 63;
    const int bm = blockIdx.y * 128, bn = blockIdx.x * 128;
    const int lrow8 = lane >> 3;
    const int pchunk = lane & 7;
    const int m_lane = lane & 15, quad = lane >> 4;
    const int wr = wave >> 1, wc = wave & 1;

    f32x4 acc[4][4] = {};

    for (int k0 = 0; k0 < K; k0 += 64) {
        #pragma unroll
        for (int c = 0; c < 4; c++) {
            int row = wave * 32 + c * 8 + lrow8;
            int gchunk = pchunk ^ (row & 7);
            const unsigned short* gpA = A + (size_t)(bm + row) * K + k0 + gchunk * 8;
            const unsigned short* gpB = Bt + (size_t)(bn + row) * K + k0 + gchunk * 8;
            __builtin_amdgcn_global_load_lds(
                (const __attribute__((address_space(1))) void*)gpA,
                (__attribute__((address_space(3))) void*)(As + (wave * 32 + c * 8) * 64),
                16, 0, 0);
            __builtin_amdgcn_global_load_lds(
                (const __attribute__((address_space(1))) void*)gpB,
                (__attribute__((address_space(3))) void*)(Bs + (wave * 32 + c * 8) * 64),
                16, 0, 0);
        }
        __syncthreads();
        #pragma unroll
        for (int kk = 0; kk < 2; kk++) {
            bf16x8 af[4], bfr[4];
            #pragma unroll
            for (int i = 0; i < 4; i++) {
                int row = wr * 64 + i * 16 + m_lane;
                int lchunk = kk * 4 + quad;
                af[i] = *(const bf16x8*)(As + row * 64 + (lchunk ^ (row & 7)) * 8);
            }
            #pragma unroll
            for (int j = 0; j < 4; j++) {
                int row = wc * 64 + j * 16 + m_lane;
                int lchunk = kk * 4 + quad;
                bfr[j] = *(const bf16x8*)(Bs + row * 64 + (lchunk ^ (row & 7)) * 8);
            }
            #pragma unroll
            for (int i = 0; i < 4; i++)
                #pragma unroll
                for (int j = 0; j < 4; j++)
                    acc[i][j] = __builtin_amdgcn_mfma_f32_16x16x32_bf16(
                        af[i], bfr[j], acc[i][j], 0, 0, 0);
        }
        __syncthreads();
    }

    // ---- fused epilogue: banded dots ----
    int cols[4];
    float uvals[4], vvals[4];
    #pragma unroll
    for (int j = 0; j < 4; j++) {
        cols[j] = bn + wc * 64 + j * 16 + m_lane;
        uvals[j] = u[cols[j]];
        vvals[j] = v[cols[j]];
    }
    #pragma unroll
    for (int i = 0; i < 4; i++) {
        #pragma unroll
        for (int r = 0; r < 4; r++) {
            int lrow = wr * 64 + i * 16 + quad * 4 + r;
            int row = bm + lrow;
            int s = row & (S_ - 1);
            bool hu = (s < S_ - 1), hd = (s > 0);
            const unsigned short* xc = A + (size_t)row * D_;
            float pu = 0.f, pd = 0.f, pau = 0.f, pav = 0.f;
            #pragma unroll
            for (int j = 0; j < 4; j++) {
                int c = cols[j];
                float a = acc[i][j][r];
                float xv = bf2f(xc[c]);
                if (hu) pu += a * bf2f(xc[c + D_]);
                if (hd) pd += a * bf2f(xc[c - D_]);
                pau += uvals[j] * xv;
                pav += vvals[j] * xv;
            }
            #pragma unroll
            for (int off = 1; off < 16; off <<= 1) {
                pu += __shfl_xor(pu, off, 64);
                pd += __shfl_xor(pd, off, 64);
                pau += __shfl_xor(pau, off, 64);
                pav += __shfl_xor(pav, off, 64);
            }
            if (m_lane == 0) {
                atomicAdd(&ydu[row], pu);
                atomicAdd(&ydd[row], pd);
                atomicAdd(&au[row], pau);
                atomicAdd(&av[row], pav);
            }
        }
    }
}

// ---------------- fused banded softmax + f64 prefix scan --------------------
__global__ void softmax_prefix(const float* __restrict__ ydu, const float* __restrict__ ydd,
                               const float* __restrict__ au, const float* __restrict__ av,
                               const float* __restrict__ c0p, const int* __restrict__ eos,
                               float* __restrict__ Pup, float* __restrict__ Pdn,
                               float* __restrict__ bg, double* __restrict__ C) {
    __shared__ float pdsh[1024];
    __shared__ double wsum[16];
    int b = blockIdx.x;
    int t = threadIdx.x;           // 0..1023 = row s
    int r = b * S_ + t;
    float c0 = *c0p;
    const float inv_d = 1.0f / D_;
    bool mu = false, md = false;
    float su = 0.f, sd = 0.f;
    if (t < S_ - 1) {
        mu = eos[(size_t)b * S_ * S_ + (size_t)t * S_ + (t + 1)] != 0;
        su = (ydu[r] + av[r] + au[r + 1] + c0) * inv_d;
    }
    if (t > 0) {
        md = eos[(size_t)b * S_ * S_ + (size_t)t * S_ + (t - 1)] != 0;
        sd = (ydd[r] + av[r] + au[r - 1] + c0) * inv_d;
    }
    float pu, pd, pb;
    if (mu && md) {
        float m = fmaxf(su, sd);
        float eu = expf(su - m), ed = expf(sd - m);
        float inv = 1.0f / (eu + ed);
        pu = eu * inv; pd = ed * inv; pb = 0.f;
    } else if (mu) { pu = 1.f; pd = 0.f; pb = 0.f; }
    else if (md)   { pu = 0.f; pd = 1.f; pb = 0.f; }
    else           { pu = pd = pb = 1.0f / S_; }
    Pup[r] = pu; Pdn[r] = pd; bg[r] = pb;
    pdsh[t] = pd;
    __syncthreads();
    double l = 0.0;
    if (t < S_ - 1) {
        float p = sqrtf(pu * pdsh[t + 1] + 1e-9f) + 1e-9f;
        l = log((double)p);
    }
    int lane = t & 63, w = t >> 6;
    double vv = l;
    #pragma unroll
    for (int off = 1; off < 64; off <<= 1) {
        double o = __shfl_up(vv, off, 64);
        if (lane >= off) vv += o;
    }
    if (lane == 63) wsum[w] = vv;
    __syncthreads();
    if (t == 0) {
        double acc = 0.0;
        #pragma unroll
        for (int i = 0; i < 16; i++) { double x = wsum[i]; wsum[i] = acc; acc += x; }
    }
    __syncthreads();
    vv += wsum[w];
    size_t base = (size_t)b * S_;
    if (t == 0) C[base] = 0.0;
    if (t < S_ - 1) C[base + t + 1] = vv;
}

// ---------------- final outputs: g and neibor -------------------------------
__global__ void write_out(const float* __restrict__ Pup, const float* __restrict__ Pdn,
                          const float* __restrict__ bg, const double* __restrict__ C,
                          float* __restrict__ out) {
    int r = blockIdx.x;
    int b = r >> 10, s = r & (S_ - 1);
    size_t rowbase = (size_t)r * S_;
    size_t bb = (size_t)b * S_;
    float pu_s = (s < S_ - 1) ? Pup[r] : 0.f;
    float pd_s = (s > 0) ? Pdn[r] : 0.f;
    float bg_s = bg[r];
    double C_s = C[r];
    int t0 = threadIdx.x * 4;
    float* gp = out;
    float* np = out + (size_t)B_ * S_ * S_;
    float4 bgv = *(const float4*)(bg + bb + t0);
    float4 gv, nv;
    #pragma unroll
    for (int j = 0; j < 4; j++) {
        int t = t0 + j;
        float P_st = (t == s + 1) ? pu_s : ((t == s - 1) ? pd_s : bg_s);
        float P_ts;
        if (t == s - 1)      P_ts = Pup[bb + t];
        else if (t == s + 1) P_ts = Pdn[bb + t];
        else                 P_ts = ((const float*)&bgv)[j];
        float neib = sqrtf(P_st * P_ts + 1e-9f);
        float g;
        if (t == s) {
            g = neib;
        } else {
            double diff = (t > s) ? (C[bb + t] - C_s) : (C_s - C[bb + t]);
            g = expf((float)diff) + 1e-9f;
        }
        ((float*)&gv)[j] = g;
        ((float*)&nv)[j] = neib;
    }
    *(float4*)(gp + rowbase + t0) = gv;
    *(float4*)(np + rowbase + t0) = nv;
}

// ---------------- launcher ---------------------------------------------------
extern "C" void kernel_launch(void* const* d_in, const int* in_sizes, int n_in,
                              void* d_out, int out_size, void* d_ws, size_t ws_size,
                              hipStream_t stream) {
    const float* ctx  = (const float*)d_in[0];
    const int*   eos  = (const int*)d_in[1];
    const float* Wq   = (const float*)d_in[2];
    const float* bq   = (const float*)d_in[3];
    const float* Wk   = (const float*)d_in[4];
    const float* bk   = (const float*)d_in[5];
    const float* ln_a = (const float*)d_in[6];
    const float* ln_b = (const float*)d_in[7];
    float* out = (float*)d_out;

    char* ws = (char*)d_ws;
    size_t off = 0;
    auto alloc = [&](size_t bytes) {
        void* p = ws + off;
        off += (bytes + 255) & ~(size_t)255;
        return p;
    };
    unsigned short* Xb  = (unsigned short*)alloc((size_t)BS * D_ * 2);
    unsigned short* Wqt = (unsigned short*)alloc((size_t)D_ * D_ * 2);
    unsigned short* Wkt = (unsigned short*)alloc((size_t)D_ * D_ * 2);
    unsigned short* Mt  = (unsigned short*)alloc((size_t)D_ * D_ * 2);
    // ---- zeroed region (contiguous): ydu, ydd, au, av, u, v, c0 ----
    float*  ydu = (float*)alloc(BS * 4);
    float*  ydd = (float*)alloc(BS * 4);
    float*  au  = (float*)alloc(BS * 4);
    float*  av  = (float*)alloc(BS * 4);
    float*  u   = (float*)alloc(D_ * 4);
    float*  v   = (float*)alloc(D_ * 4);
    float*  c0  = (float*)alloc(4);
    size_t zero_bytes = (size_t)((char*)c0 - (char*)ydu) + 256;
    // ---- rest ----
    float*  Pup = (float*)alloc(BS * 4);
    float*  Pdn = (float*)alloc(BS * 4);
    float*  bg  = (float*)alloc(BS * 4);
    double* Cp  = (double*)alloc(BS * 8);

    // 0. zero the atomic-accumulate targets
    hipMemsetAsync(ydu, 0, zero_bytes, stream);
    // 1. LayerNorm -> bf16
    ln_kernel<<<BS, 256, 0, stream>>>(ctx, ln_a, ln_b, Xb);
    // 2. transpose-convert Wq, Wk
    transpose2_bf16<<<dim3(32, 32, 2), dim3(32, 8), 0, stream>>>(Wq, Wk, Wqt, Wkt);
    // 3. bias terms
    bias_terms<<<8, 256, 0, stream>>>(Wq, Wk, bq, bk, u, v, c0);
    // 4. Mt[n][k] = sum_d Wk[d][n] Wq[d][k]
    gemm_bt64<<<dim3(16, 16), 256, 0, stream>>>(Wkt, Wqt, Mt, D_, D_, D_);
    // 5. fused: Y = Xb Mt^T (registers only) + banded dots
    gemm_fused<<<dim3(8, 64), 256, 0, stream>>>(Xb, Mt, u, v, ydu, ydd, au, av,
                                                BS, D_, D_);
    // 6. fused banded softmax + prefix scan
    softmax_prefix<<<B_, 1024, 0, stream>>>(ydu, ydd, au, av, c0, eos, Pup, Pdn, bg, Cp);
    // 7. outputs
    write_out<<<BS, 256, 0, stream>>>(Pup, Pdn, bg, Cp, out);
}